// Round 1
// baseline (54.896 us; speedup 1.0000x reference)
//
#include <hip/hip_runtime.h>
#include <cmath>

#define BATCH 8192
#define SEGLEN 32
#define ACCUMD 256

__device__ __forceinline__ float crelu(float x) {
    float c = fminf(fmaxf(x, -1.0f), 0.9921875f);   // clamp [-1, 127/128]
    return fmaf(0.1f, x - c, c);                    // leak outside the clamp
}

__global__ __launch_bounds__(256) void nnue_kernel(
    const int* __restrict__ indices,      // [B*L]
    const int* __restrict__ which_model,  // [B]
    const int* __restrict__ lengths,      // [B]
    const float* __restrict__ embed,      // [F][256]
    const float* __restrict__ main_bias,  // [256]
    const float* __restrict__ W1,         // [16][16][256]
    const float* __restrict__ b1,         // [16][16]
    const float* __restrict__ W2,         // [16][32][16]
    const float* __restrict__ b2,         // [16][32]
    const float* __restrict__ W3,         // [16][1][32]
    const float* __restrict__ b3,         // [16][1]
    float* __restrict__ out)              // [B]
{
    const int b = blockIdx.x;
    const int t = threadIdx.x;

    __shared__ int   sidx[SEGLEN];
    __shared__ float4 part[4][64];
    __shared__ float emb_s[ACCUMD];
    __shared__ float h1_s[16];
    __shared__ float h2_s[32];
    __shared__ float psqt_s;
    __shared__ int   e_s;

    if (t < SEGLEN) sidx[t] = indices[b * SEGLEN + t];
    if (t == 0) {
        int gp = lengths[b] / 17;          // game phase 0..3
        e_s = which_model[b] + gp * 4;     // selected expert 0..15
    }
    __syncthreads();

    // ---- Phase 1: gather-sum of 32 embedding rows (float4 vectorized) ----
    const int g    = t >> 6;   // wave id 0..3 -> owns 8 rows
    const int lane = t & 63;   // float4 column chunk 0..63 (dims 4*lane..4*lane+3)
    const float4* embed4 = reinterpret_cast<const float4*>(embed);
    float4 acc = make_float4(0.f, 0.f, 0.f, 0.f);
    #pragma unroll
    for (int l = 0; l < 8; ++l) {
        long row = (long)sidx[g * 8 + l];
        float4 v = embed4[row * 64 + lane];
        acc.x += v.x; acc.y += v.y; acc.z += v.z; acc.w += v.w;
    }
    part[g][lane] = acc;
    __syncthreads();

    // ---- Reduce 4 wave-partials, add bias, capture psqt, apply crelu ----
    if (t < 64) {
        float4 s0 = part[0][t], s1 = part[1][t], s2 = part[2][t], s3 = part[3][t];
        const float4* mb4 = reinterpret_cast<const float4*>(main_bias);
        float4 mb = mb4[t];
        float4 tot;
        tot.x = s0.x + s1.x + s2.x + s3.x + mb.x;
        tot.y = s0.y + s1.y + s2.y + s3.y + mb.y;
        tot.z = s0.z + s1.z + s2.z + s3.z + mb.z;
        tot.w = s0.w + s1.w + s2.w + s3.w + mb.w;
        if (t == 0) psqt_s = tot.x;        // pre-activation accum[:,0]
        emb_s[4 * t + 0] = crelu(tot.x);
        emb_s[4 * t + 1] = crelu(tot.y);
        emb_s[4 * t + 2] = crelu(tot.z);
        emb_s[4 * t + 3] = crelu(tot.w);
    }
    __syncthreads();

    const int e = e_s;

    // ---- Layer 1: 256 -> 16, one 16-lane group per output neuron ----
    {
        const int o = t >> 4;   // 0..15
        const int j = t & 15;
        const float* w = W1 + ((e * 16 + o) << 8);
        float p = 0.f;
        #pragma unroll
        for (int d = j; d < ACCUMD; d += 16) p = fmaf(emb_s[d], w[d], p);
        #pragma unroll
        for (int m = 8; m >= 1; m >>= 1) p += __shfl_xor(p, m, 16);
        if (j == 0) h1_s[o] = crelu(p + b1[e * 16 + o]);
    }
    __syncthreads();

    // ---- Layer 2: 16 -> 32 ----
    if (t < 32) {
        const float* w = W2 + (e * 32 + t) * 16;
        float p = b2[e * 32 + t];
        #pragma unroll
        for (int j = 0; j < 16; ++j) p = fmaf(h1_s[j], w[j], p);
        h2_s[t] = crelu(p);
    }
    __syncthreads();

    // ---- Layer 3: 32 -> 1, shuffle reduce, tanh output ----
    if (t < 32) {
        float p = h2_s[t] * W3[e * 32 + t];
        #pragma unroll
        for (int m = 16; m >= 1; m >>= 1) p += __shfl_xor(p, m, 32);
        if (t == 0) out[b] = tanhf(p + b3[e] + psqt_s);
    }
}

extern "C" void kernel_launch(void* const* d_in, const int* in_sizes, int n_in,
                              void* d_out, int out_size, void* d_ws, size_t ws_size,
                              hipStream_t stream) {
    const int*   indices     = (const int*)d_in[0];
    // d_in[1] = offsets: always arange(B)*32, unused
    const int*   which_model = (const int*)d_in[2];
    const int*   lengths     = (const int*)d_in[3];
    const float* embed       = (const float*)d_in[4];
    const float* main_bias   = (const float*)d_in[5];
    const float* W1          = (const float*)d_in[6];
    const float* b1          = (const float*)d_in[7];
    const float* W2          = (const float*)d_in[8];
    const float* b2          = (const float*)d_in[9];
    const float* W3          = (const float*)d_in[10];
    const float* b3          = (const float*)d_in[11];
    float* out = (float*)d_out;

    nnue_kernel<<<BATCH, 256, 0, stream>>>(indices, which_model, lengths,
                                           embed, main_bias, W1, b1, W2, b2, W3, b3,
                                           out);
}

// Round 2
// 51.349 us; speedup vs baseline: 1.0691x; 1.0691x over previous
//
#include <hip/hip_runtime.h>
#include <cmath>

#define BATCH 8192
#define SEGLEN 32
#define ACCUMD 256

__device__ __forceinline__ float crelu(float x) {
    float c = fminf(fmaxf(x, -1.0f), 0.9921875f);   // clamp [-1, 127/128]
    return fmaf(0.1f, x - c, c);                    // leak outside the clamp
}

__global__ __launch_bounds__(256) void nnue_kernel(
    const int* __restrict__ indices,      // [B*L]
    const int* __restrict__ which_model,  // [B]
    const int* __restrict__ lengths,      // [B]
    const float* __restrict__ embed,      // [F][256]
    const float* __restrict__ main_bias,  // [256]
    const float* __restrict__ W1,         // [16][16][256]
    const float* __restrict__ b1,         // [16][16]
    const float* __restrict__ W2,         // [16][32][16]
    const float* __restrict__ b2,         // [16][32]
    const float* __restrict__ W3,         // [16][1][32]
    const float* __restrict__ b3,         // [16][1]
    float* __restrict__ out)              // [B]
{
    const int b = blockIdx.x;
    const int t = threadIdx.x;
    const int g    = t >> 6;   // wave id 0..3 -> owns 8 rows
    const int lane = t & 63;   // float4 column chunk 0..63

    __shared__ float4 part[4][64];
    __shared__ float emb_s[ACCUMD];
    __shared__ float h1_s[16];

    // ---- Phase 1: gather 32 embedding rows, 8 per wave, all loads in flight ----
    const float4* embed4 = reinterpret_cast<const float4*>(embed);

    long rows[8];
    #pragma unroll
    for (int l = 0; l < 8; ++l)
        rows[l] = (long)indices[b * SEGLEN + g * 8 + l];   // wave-uniform -> scalar loads

    float4 v[8];
    #pragma unroll
    for (int l = 0; l < 8; ++l)
        v[l] = embed4[rows[l] * 64 + lane];                // 8 independent loads in flight

    float4 acc;
    acc.x = ((v[0].x + v[1].x) + (v[2].x + v[3].x)) + ((v[4].x + v[5].x) + (v[6].x + v[7].x));
    acc.y = ((v[0].y + v[1].y) + (v[2].y + v[3].y)) + ((v[4].y + v[5].y) + (v[6].y + v[7].y));
    acc.z = ((v[0].z + v[1].z) + (v[2].z + v[3].z)) + ((v[4].z + v[5].z) + (v[6].z + v[7].z));
    acc.w = ((v[0].w + v[1].w) + (v[2].w + v[3].w)) + ((v[4].w + v[5].w) + (v[6].w + v[7].w));
    part[g][lane] = acc;

    // expert selector: uniform scalar loads, computed by every thread
    const int e = which_model[b] + (lengths[b] / 17) * 4;

    float psqt = 0.f;   // valid in thread 0 only
    __syncthreads();

    // ---- Reduce 4 wave-partials, add bias, capture psqt, apply crelu ----
    if (t < 64) {
        float4 s0 = part[0][t], s1 = part[1][t], s2 = part[2][t], s3 = part[3][t];
        const float4* mb4 = reinterpret_cast<const float4*>(main_bias);
        float4 mb = mb4[t];
        float4 tot;
        tot.x = (s0.x + s1.x) + (s2.x + s3.x) + mb.x;
        tot.y = (s0.y + s1.y) + (s2.y + s3.y) + mb.y;
        tot.z = (s0.z + s1.z) + (s2.z + s3.z) + mb.z;
        tot.w = (s0.w + s1.w) + (s2.w + s3.w) + mb.w;
        if (t == 0) psqt = tot.x;          // pre-activation accum[:,0]
        emb_s[4 * t + 0] = crelu(tot.x);
        emb_s[4 * t + 1] = crelu(tot.y);
        emb_s[4 * t + 2] = crelu(tot.z);
        emb_s[4 * t + 3] = crelu(tot.w);
    }
    __syncthreads();

    // ---- Layer 1: 256 -> 16, one 16-lane group per output neuron ----
    {
        const int o = t >> 4;   // 0..15
        const int j = t & 15;
        const float* w = W1 + ((e * 16 + o) << 8);
        float p = 0.f;
        #pragma unroll
        for (int d = j; d < ACCUMD; d += 16) p = fmaf(emb_s[d], w[d], p);
        #pragma unroll
        for (int m = 8; m >= 1; m >>= 1) p += __shfl_xor(p, m, 16);
        if (j == 0) h1_s[o] = crelu(p + b1[e * 16 + o]);
    }
    __syncthreads();

    // ---- Layers 2+3 fused in wave 0: 16 -> 32 -> 1, shuffle reduce, tanh ----
    if (t < 32) {
        const float* w = W2 + (e * 32 + t) * 16;
        float p = b2[e * 32 + t];
        #pragma unroll
        for (int j = 0; j < 16; ++j) p = fmaf(h1_s[j], w[j], p);
        float q = crelu(p) * W3[e * 32 + t];
        #pragma unroll
        for (int m = 16; m >= 1; m >>= 1) q += __shfl_xor(q, m, 32);
        if (t == 0) out[b] = tanhf(q + b3[e] + psqt);
    }
}

extern "C" void kernel_launch(void* const* d_in, const int* in_sizes, int n_in,
                              void* d_out, int out_size, void* d_ws, size_t ws_size,
                              hipStream_t stream) {
    const int*   indices     = (const int*)d_in[0];
    // d_in[1] = offsets: always arange(B)*32, unused
    const int*   which_model = (const int*)d_in[2];
    const int*   lengths     = (const int*)d_in[3];
    const float* embed       = (const float*)d_in[4];
    const float* main_bias   = (const float*)d_in[5];
    const float* W1          = (const float*)d_in[6];
    const float* b1          = (const float*)d_in[7];
    const float* W2          = (const float*)d_in[8];
    const float* b2          = (const float*)d_in[9];
    const float* W3          = (const float*)d_in[10];
    const float* b3          = (const float*)d_in[11];
    float* out = (float*)d_out;

    nnue_kernel<<<BATCH, 256, 0, stream>>>(indices, which_model, lengths,
                                           embed, main_bias, W1, b1, W2, b2, W3, b3,
                                           out);
}

// Round 3
// 43.460 us; speedup vs baseline: 1.2631x; 1.1815x over previous
//
#include <hip/hip_runtime.h>
#include <cmath>

#define BATCH 8192
#define ACCUMD 256

__device__ __forceinline__ float crelu(float x) {
    float c = fminf(fmaxf(x, -1.0f), 0.9921875f);   // clamp [-1, 127/128]
    return fmaf(0.1f, x - c, c);                    // leak outside the clamp
}

__device__ __forceinline__ void f4add(float4& a, const float4& v) {
    a.x += v.x; a.y += v.y; a.z += v.z; a.w += v.w;
}

__global__ __launch_bounds__(256) void nnue_kernel(
    const int* __restrict__ indices,      // [B*32]
    const int* __restrict__ which_model,  // [B]
    const int* __restrict__ lengths,      // [B]
    const float* __restrict__ embed,      // [F][256]
    const float* __restrict__ main_bias,  // [256]
    const float* __restrict__ W1,         // [16][16][256]
    const float* __restrict__ b1,         // [16][16]
    const float* __restrict__ W2,         // [16][32][16]
    const float* __restrict__ b2,         // [16][32]
    const float* __restrict__ W3,         // [16][1][32]
    const float* __restrict__ b3,         // [16][1]
    float* __restrict__ out)              // [B]
{
    const int w    = threadIdx.x >> 6;    // wave id 0..3 (independent workers)
    const int lane = threadIdx.x & 63;
    const int b    = blockIdx.x * 4 + w;  // batch element owned by this wave

    __shared__ float emb_s[4][ACCUMD];    // per-wave scratch, no cross-wave sharing
    __shared__ float h1_s[4][16];

    const float4* embed4 = reinterpret_cast<const float4*>(embed);
    const int* idx = indices + b * 32;    // wave-uniform -> scalar loads

    // ---- Gather-sum of 32 rows, 16-deep double-buffered load pipeline ----
    float4 acc = make_float4(0.f, 0.f, 0.f, 0.f);
    float4 va[8], vb[8];
    #pragma unroll
    for (int l = 0; l < 8; ++l) va[l] = embed4[(long)idx[l]      * 64 + lane];
    #pragma unroll
    for (int l = 0; l < 8; ++l) vb[l] = embed4[(long)idx[8 + l]  * 64 + lane];
    #pragma unroll
    for (int l = 0; l < 8; ++l) { f4add(acc, va[l]); va[l] = embed4[(long)idx[16 + l] * 64 + lane]; }
    #pragma unroll
    for (int l = 0; l < 8; ++l) { f4add(acc, vb[l]); vb[l] = embed4[(long)idx[24 + l] * 64 + lane]; }
    #pragma unroll
    for (int l = 0; l < 8; ++l) f4add(acc, va[l]);
    #pragma unroll
    for (int l = 0; l < 8; ++l) f4add(acc, vb[l]);

    // ---- Bias, psqt (pre-activation dim 0, lives in lane 0), crelu -> LDS ----
    const float4* mb4 = reinterpret_cast<const float4*>(main_bias);
    float4 tot = acc;
    f4add(tot, mb4[lane]);
    const float psqt = tot.x;             // valid in lane 0 only
    float4 ev;
    ev.x = crelu(tot.x); ev.y = crelu(tot.y); ev.z = crelu(tot.z); ev.w = crelu(tot.w);
    *reinterpret_cast<float4*>(&emb_s[w][4 * lane]) = ev;
    __builtin_amdgcn_wave_barrier();      // compiler ordering; wave-sync LDS, no __syncthreads

    const int e = which_model[b] + (lengths[b] / 17) * 4;   // uniform scalar loads

    // ---- Layer 1: 256 -> 16; 4 lanes per output neuron ----
    {
        const int o = lane >> 2;          // 0..15
        const int j = lane & 3;           // 0..3
        const float4* w1q = reinterpret_cast<const float4*>(W1 + ((e * 16 + o) << 8));
        float p = 0.f;
        #pragma unroll
        for (int k = 0; k < 16; ++k) {
            float4 x = *reinterpret_cast<const float4*>(&emb_s[w][(4 * k + j) * 4]);
            float4 wv = w1q[4 * k + j];
            p = fmaf(x.x, wv.x, fmaf(x.y, wv.y, fmaf(x.z, wv.z, fmaf(x.w, wv.w, p))));
        }
        p += __shfl_xor(p, 1);
        p += __shfl_xor(p, 2);            // all 4 lanes of the group now hold the sum
        if (j == 0) h1_s[w][o] = crelu(p + b1[e * 16 + o]);
    }
    __builtin_amdgcn_wave_barrier();

    // ---- Layers 2+3 fused in lanes 0..31: 16 -> 32 -> 1 ----
    if (lane < 32) {
        const float4* h14 = reinterpret_cast<const float4*>(h1_s[w]);
        const float4* w24 = reinterpret_cast<const float4*>(W2 + (e * 32 + lane) * 16);
        float p = b2[e * 32 + lane];
        #pragma unroll
        for (int k = 0; k < 4; ++k) {
            float4 h = h14[k]; float4 wv = w24[k];
            p = fmaf(h.x, wv.x, fmaf(h.y, wv.y, fmaf(h.z, wv.z, fmaf(h.w, wv.w, p))));
        }
        float q = crelu(p) * W3[e * 32 + lane];
        #pragma unroll
        for (int m = 16; m >= 1; m >>= 1) q += __shfl_xor(q, m, 32);
        if (lane == 0) out[b] = tanhf(q + b3[e] + psqt);
    }
}

extern "C" void kernel_launch(void* const* d_in, const int* in_sizes, int n_in,
                              void* d_out, int out_size, void* d_ws, size_t ws_size,
                              hipStream_t stream) {
    const int*   indices     = (const int*)d_in[0];
    // d_in[1] = offsets: always arange(B)*32, unused
    const int*   which_model = (const int*)d_in[2];
    const int*   lengths     = (const int*)d_in[3];
    const float* embed       = (const float*)d_in[4];
    const float* main_bias   = (const float*)d_in[5];
    const float* W1          = (const float*)d_in[6];
    const float* b1          = (const float*)d_in[7];
    const float* W2          = (const float*)d_in[8];
    const float* b2          = (const float*)d_in[9];
    const float* W3          = (const float*)d_in[10];
    const float* b3          = (const float*)d_in[11];
    float* out = (float*)d_out;

    nnue_kernel<<<BATCH / 4, 256, 0, stream>>>(indices, which_model, lengths,
                                               embed, main_bias, W1, b1, W2, b2, W3, b3,
                                               out);
}